// Round 1
// baseline (1465.015 us; speedup 1.0000x reference)
//
#include <hip/hip_runtime.h>

#define NM_ 1500000
#define NT_ 100000
#define NF_ 1500000
#define NTOT (NM_ + NT_ + NF_)
#define NBX_ 1024
#define NBY_ 1024
#define NBINS (NBX_ * NBY_)
#define KFIX 22

__constant__ float TD_ = 0.9f;

// One thread per (fixed node, x-column k). Each thread owns one bin column
// of the node's footprint and walks its y-span (contiguous dmap addresses).
__global__ void scatter_fixed_k(const float* __restrict__ xs, const float* __restrict__ ys,
                                const float* __restrict__ sxs, const float* __restrict__ sys,
                                float* __restrict__ dmap) {
    int gid = blockIdx.x * blockDim.x + threadIdx.x;
    if (gid >= NT_ * KFIX) return;
    int node = gid / KFIX;
    int k = gid - node * KFIX;
    int i = NM_ + node;
    float xi = xs[i], yi = ys[i], sxi = sxs[i], syi = sys[i];
    int bx = (int)floorf(xi) + k;
    if (bx < 0 || bx >= NBX_) return;
    float ox = fminf(xi + sxi, (float)(bx + 1)) - fmaxf(xi, (float)bx);
    if (ox <= 0.0f) return;
    ox *= 0.9f;  // TD weight applied to the fixed-node (init) map
    float yhi = yi + syi;
    int by0 = max((int)floorf(yi), 0);
    int bye = min((int)floorf(yhi), NBY_ - 1);
    float* row = dmap + (size_t)bx * NBY_;
    for (int by = by0; by <= bye; ++by) {
        float oy = fminf(yhi, (float)(by + 1)) - fmaxf(yi, (float)by);
        if (oy > 0.0f) atomicAdd(row + by, ox * oy);
    }
}

// One thread per movable/filler node (span is at most 3x3 bins).
__global__ void scatter_mov_k(const float* __restrict__ xs, const float* __restrict__ ys,
                              const float* __restrict__ sxs, const float* __restrict__ sys,
                              float* __restrict__ dmap) {
    int t = blockIdx.x * blockDim.x + threadIdx.x;
    if (t >= NM_ + NF_) return;
    int i = (t < NM_) ? t : t + NT_;   // skip the fixed-terminal segment
    float xi = xs[i], yi = ys[i], sxi = sxs[i], syi = sys[i];
    float xhi = xi + sxi, yhi = yi + syi;
    int bx0 = max((int)floorf(xi), 0);
    int bxe = min((int)floorf(xhi), NBX_ - 1);
    int by0 = max((int)floorf(yi), 0);
    int bye = min((int)floorf(yhi), NBY_ - 1);
    for (int bx = bx0; bx <= bxe; ++bx) {
        float ox = fminf(xhi, (float)(bx + 1)) - fmaxf(xi, (float)bx);
        if (ox <= 0.0f) continue;
        float* row = dmap + (size_t)bx * NBY_;
        for (int by = by0; by <= bye; ++by) {
            float oy = fminf(yhi, (float)(by + 1)) - fmaxf(yi, (float)by);
            if (oy > 0.0f) atomicAdd(row + by, ox * oy);
        }
    }
}

__device__ inline void wave_red(float& s, float& m) {
    for (int off = 32; off > 0; off >>= 1) {
        s += __shfl_down(s, off, 64);
        m = fmaxf(m, __shfl_down(m, off, 64));
    }
}

__global__ void reduce1_k(const float* __restrict__ dmap, const unsigned char* __restrict__ pm,
                          float* __restrict__ psum, float* __restrict__ pmax) {
    float s = 0.0f, m = 0.0f;
    int stride = gridDim.x * blockDim.x;
    for (int i = blockIdx.x * blockDim.x + threadIdx.x; i < NBINS; i += stride) {
        float d = dmap[i];
        if (pm[i]) d = 0.9f;          // padding_mask -> TD * bin_area
        s += fmaxf(d - 0.9f, 0.0f);
        m = fmaxf(m, d);
    }
    __shared__ float ss[4], sm[4];
    int lane = threadIdx.x & 63, wv = threadIdx.x >> 6;
    wave_red(s, m);
    if (lane == 0) { ss[wv] = s; sm[wv] = m; }
    __syncthreads();
    if (threadIdx.x == 0) {
        float S = ss[0], M = sm[0];
        for (int w = 1; w < (int)(blockDim.x >> 6); ++w) { S += ss[w]; M = fmaxf(M, sm[w]); }
        psum[blockIdx.x] = S;
        pmax[blockIdx.x] = M;
    }
}

__global__ void reduce2_k(const float* __restrict__ psum, const float* __restrict__ pmax,
                          float* __restrict__ out, int n) {
    float s = 0.0f, m = 0.0f;
    for (int i = threadIdx.x; i < n; i += blockDim.x) { s += psum[i]; m = fmaxf(m, pmax[i]); }
    __shared__ float ss[16], sm[16];
    int lane = threadIdx.x & 63, wv = threadIdx.x >> 6;
    wave_red(s, m);
    if (lane == 0) { ss[wv] = s; sm[wv] = m; }
    __syncthreads();
    if (threadIdx.x == 0) {
        float S = 0.0f, M = 0.0f;
        for (int w = 0; w < (int)(blockDim.x >> 6); ++w) { S += ss[w]; M = fmaxf(M, sm[w]); }
        out[0] = S;        // density_cost
        out[1] = M;        // max_density (bin_area == 1)
    }
}

extern "C" void kernel_launch(void* const* d_in, const int* in_sizes, int n_in,
                              void* d_out, int out_size, void* d_ws, size_t ws_size,
                              hipStream_t stream) {
    const float* pos = (const float*)d_in[0];
    const float* xs = pos;
    const float* ys = pos + NTOT;
    const float* sxs = (const float*)d_in[1];
    const float* sys = (const float*)d_in[2];
    const unsigned char* pm = (const unsigned char*)d_in[5];
    float* out = (float*)d_out;

    float* dmap = (float*)d_ws;                 // 4 MB
    float* psum = dmap + NBINS;                 // 4 KB
    float* pmax = psum + 1024;                  // 4 KB

    hipMemsetAsync(d_ws, 0, (size_t)NBINS * sizeof(float), stream);

    {
        int total = NT_ * KFIX;
        scatter_fixed_k<<<(total + 255) / 256, 256, 0, stream>>>(xs, ys, sxs, sys, dmap);
    }
    {
        int total = NM_ + NF_;
        scatter_mov_k<<<(total + 255) / 256, 256, 0, stream>>>(xs, ys, sxs, sys, dmap);
    }
    reduce1_k<<<1024, 256, 0, stream>>>(dmap, pm, psum, pmax);
    reduce2_k<<<1, 1024, 0, stream>>>(psum, pmax, out, 1024);
}

// Round 2
// 850.620 us; speedup vs baseline: 1.7223x; 1.7223x over previous
//
#include <hip/hip_runtime.h>

#define NM_ 1500000
#define NT_ 100000
#define NF_ 1500000
#define NTOT (NM_ + NT_ + NF_)
#define NBX_ 1024
#define NBY_ 1024
#define NBINS (NBX_ * NBY_)
#define TDv 0.9f
#define SEGS 16
#define SEGROWS (NBX_ / SEGS)          /* 64 rows per segment */
#define MOV_BLOCKS ((NM_ + NF_ + 255) / 256)
#define FIX_BLOCKS ((NT_ + 255) / 256)

typedef float v2f __attribute__((ext_vector_type(2)));

#if __has_builtin(__builtin_amdgcn_global_atomic_fadd_v2f32)
typedef __attribute__((address_space(1))) v2f* gv2f_p;
__device__ inline void pk_add(float* p, float w0, float w1) {
    v2f v; v.x = w0; v.y = w1;
    __builtin_amdgcn_global_atomic_fadd_v2f32((gv2f_p)p, v);
}
#else
__device__ inline void pk_add(float* p, float w0, float w1) {
    if (w0 != 0.0f) atomicAdd(p, w0);
    if (w1 != 0.0f) atomicAdd(p + 1, w1);
}
#endif

// Fused scatter: blocks [0, MOV_BLOCKS) do movable/filler nodes (direct packed
// atomics, footprint <= 3x3); blocks [MOV_BLOCKS, +FIX_BLOCKS) do fixed nodes
// via the rank-1 difference-map trick (16 point atomics/node instead of ~144).
// dmap = S + Py(U) + Px(V) + PxPy(W), all fixed contributions pre-scaled by TD.
__global__ void scatter_all_k(const float* __restrict__ xs, const float* __restrict__ ys,
                              const float* __restrict__ sxs, const float* __restrict__ sys,
                              float* __restrict__ S, float* __restrict__ U,
                              float* __restrict__ V, float* __restrict__ W) {
    int b = blockIdx.x;
    if (b < MOV_BLOCKS) {
        int t = b * 256 + threadIdx.x;
        if (t >= NM_ + NF_) return;
        int i = (t < NM_) ? t : t + NT_;           // skip fixed segment
        float xi = xs[i], yi = ys[i];
        float xhi = xi + sxs[i], yhi = yi + sys[i];
        int bx0 = (int)xi, bxe = (int)xhi;         // x>=0 -> trunc == floor
        int by0 = (int)yi, bye = (int)yhi;         // always inside [0,1023]
        int p0 = by0 & ~1;                         // 8B-aligned start for pk atomics
        for (int bx = bx0; bx <= bxe; ++bx) {
            float ox = fminf(xhi, (float)(bx + 1)) - fmaxf(xi, (float)bx);
            float* row = S + bx * NBY_;
            for (int p = p0; p <= bye; p += 2) {
                float oy0 = fminf(yhi, (float)(p + 1)) - fmaxf(yi, (float)p);
                float oy1 = fminf(yhi, (float)(p + 2)) - fmaxf(yi, (float)(p + 1));
                float w0 = (p >= by0) ? ox * fmaxf(oy0, 0.0f) : 0.0f;
                float w1 = (p + 1 <= bye) ? ox * fmaxf(oy1, 0.0f) : 0.0f;
                pk_add(row + p, w0, w1);
            }
        }
    } else {
        int t = (b - MOV_BLOCKS) * 256 + threadIdx.x;
        if (t >= NT_) return;
        int i = NM_ + t;
        float xi = xs[i], yi = ys[i];
        float xhi = xi + sxs[i], yhi = yi + sys[i];
        int bx0 = (int)xi, bx1 = (int)xhi;         // bx1 <= 1022 (x+sx < 1023)
        int by0 = (int)yi, by1 = (int)yhi;
        float alpha = (float)bx0 - xi;             // (a-1) in (-1, 0]
        float beta  = xhi - (float)(bx1 + 1);      // (b-1)
        float gamma = (float)by0 - yi;
        float delta = yhi - (float)(by1 + 1);
        // point terms -> S
        atomicAdd(S + bx0 * NBY_ + by0, TDv * alpha * gamma);
        atomicAdd(S + bx0 * NBY_ + by1, TDv * alpha * delta);
        atomicAdd(S + bx1 * NBY_ + by0, TDv * beta * gamma);
        atomicAdd(S + bx1 * NBY_ + by1, TDv * beta * delta);
        // vertical segments (prefix along y) -> U
        atomicAdd(U + bx0 * NBY_ + by0,      TDv * alpha);
        atomicAdd(U + bx0 * NBY_ + by1 + 1, -TDv * alpha);
        atomicAdd(U + bx1 * NBY_ + by0,      TDv * beta);
        atomicAdd(U + bx1 * NBY_ + by1 + 1, -TDv * beta);
        // horizontal segments (prefix along x) -> V
        atomicAdd(V + bx0 * NBY_ + by0,       TDv * gamma);
        atomicAdd(V + (bx1 + 1) * NBY_ + by0, -TDv * gamma);
        atomicAdd(V + bx0 * NBY_ + by1,       TDv * delta);
        atomicAdd(V + (bx1 + 1) * NBY_ + by1, -TDv * delta);
        // rectangle (prefix along x and y) -> W
        atomicAdd(W + bx0 * NBY_ + by0,            TDv);
        atomicAdd(W + (bx1 + 1) * NBY_ + by0,     -TDv);
        atomicAdd(W + bx0 * NBY_ + by1 + 1,       -TDv);
        atomicAdd(W + (bx1 + 1) * NBY_ + by1 + 1,  TDv);
    }
}

__device__ inline void scan_row(float* rowbase, float* wt) {
    int t = threadIdx.x, lane = t & 63, wv = t >> 6;
    float4 v = ((float4*)rowbase)[t];
    v.y += v.x; v.z += v.y; v.w += v.z;
    float tot = v.w, run = tot;
    for (int off = 1; off < 64; off <<= 1) {
        float n = __shfl_up(run, off, 64);
        if (lane >= off) run += n;
    }
    if (lane == 63) wt[wv] = run;
    __syncthreads();
    float base = run - tot;                 // exclusive within wave
    for (int w = 0; w < wv; ++w) base += wt[w];
    v.x += base; v.y += base; v.z += base; v.w += base;
    ((float4*)rowbase)[t] = v;
}

// In-place inclusive prefix sum along y (one block per bx row) of U and W.
__global__ void scan_y_k(float* __restrict__ U, float* __restrict__ W) {
    __shared__ float wt[8];
    scan_row(U + (size_t)blockIdx.x * NBY_, wt);
    __syncthreads();
    scan_row(W + (size_t)blockIdx.x * NBY_, wt + 4);
}

// Per-segment column sums of V and W' (for the x-prefix carries).
__global__ void colsum_k(const float* __restrict__ V, const float* __restrict__ W,
                         float* __restrict__ segV, float* __restrict__ segW) {
    int seg = blockIdx.x >> 2;
    int by = (blockIdx.x & 3) * 256 + threadIdx.x;
    float sv = 0.0f, sw = 0.0f;
    int r0 = seg * SEGROWS;
    for (int r = 0; r < SEGROWS; ++r) {
        sv += V[(r0 + r) * NBY_ + by];
        sw += W[(r0 + r) * NBY_ + by];
    }
    segV[seg * NBY_ + by] = sv;
    segW[seg * NBY_ + by] = sw;
}

__device__ inline void wave_red(float& s, float& m) {
    for (int off = 32; off > 0; off >>= 1) {
        s += __shfl_down(s, off, 64);
        m = fmaxf(m, __shfl_down(m, off, 64));
    }
}

// Final: reconstruct d = S + U' + Px(V) + Px(W') on the fly, reduce sum/max.
__global__ void final_k(const float* __restrict__ S, const float* __restrict__ U,
                        const float* __restrict__ V, const float* __restrict__ W,
                        const float* __restrict__ segV, const float* __restrict__ segW,
                        const unsigned char* __restrict__ pm,
                        float* __restrict__ psum, float* __restrict__ pmax) {
    int seg = blockIdx.x >> 2;
    int by = (blockIdx.x & 3) * 256 + threadIdx.x;
    float rV = 0.0f, rW = 0.0f;
    for (int s = 0; s < seg; ++s) { rV += segV[s * NBY_ + by]; rW += segW[s * NBY_ + by]; }
    float acc = 0.0f, mx = 0.0f;
    int r0 = seg * SEGROWS;
    for (int r = 0; r < SEGROWS; ++r) {
        int idx = (r0 + r) * NBY_ + by;
        rV += V[idx]; rW += W[idx];
        float d = S[idx] + U[idx] + rV + rW;
        if (pm[idx]) d = TDv;
        acc += fmaxf(d - TDv, 0.0f);
        mx = fmaxf(mx, d);
    }
    __shared__ float ss[4], sm[4];
    int lane = threadIdx.x & 63, wv = threadIdx.x >> 6;
    wave_red(acc, mx);
    if (lane == 0) { ss[wv] = acc; sm[wv] = mx; }
    __syncthreads();
    if (threadIdx.x == 0) {
        float Sv = ss[0], M = sm[0];
        for (int w = 1; w < 4; ++w) { Sv += ss[w]; M = fmaxf(M, sm[w]); }
        psum[blockIdx.x] = Sv;
        pmax[blockIdx.x] = M;
    }
}

__global__ void combine_k(const float* __restrict__ psum, const float* __restrict__ pmax,
                          float* __restrict__ out, int n) {
    float s = 0.0f, m = 0.0f;
    for (int i = threadIdx.x; i < n; i += 64) { s += psum[i]; m = fmaxf(m, pmax[i]); }
    wave_red(s, m);
    if (threadIdx.x == 0) { out[0] = s; out[1] = m; }
}

// ---------------- fallback (round-1) path, used if ws too small --------------
__global__ void scatter_fixed_k(const float* __restrict__ xs, const float* __restrict__ ys,
                                const float* __restrict__ sxs, const float* __restrict__ sys,
                                float* __restrict__ dmap) {
    int gid = blockIdx.x * blockDim.x + threadIdx.x;
    if (gid >= NT_ * 22) return;
    int node = gid / 22, k = gid - node * 22, i = NM_ + node;
    float xi = xs[i], yi = ys[i], sxi = sxs[i], syi = sys[i];
    int bx = (int)xi + k;
    if (bx >= NBX_) return;
    float ox = fminf(xi + sxi, (float)(bx + 1)) - fmaxf(xi, (float)bx);
    if (ox <= 0.0f) return;
    ox *= TDv;
    float yhi = yi + syi;
    int by0 = (int)yi, bye = min((int)yhi, NBY_ - 1);
    float* row = dmap + (size_t)bx * NBY_;
    for (int by = by0; by <= bye; ++by) {
        float oy = fminf(yhi, (float)(by + 1)) - fmaxf(yi, (float)by);
        if (oy > 0.0f) atomicAdd(row + by, ox * oy);
    }
}
__global__ void scatter_mov_k(const float* __restrict__ xs, const float* __restrict__ ys,
                              const float* __restrict__ sxs, const float* __restrict__ sys,
                              float* __restrict__ dmap) {
    int t = blockIdx.x * blockDim.x + threadIdx.x;
    if (t >= NM_ + NF_) return;
    int i = (t < NM_) ? t : t + NT_;
    float xi = xs[i], yi = ys[i];
    float xhi = xi + sxs[i], yhi = yi + sys[i];
    int bx0 = (int)xi, bxe = (int)xhi, by0 = (int)yi, bye = (int)yhi;
    for (int bx = bx0; bx <= bxe; ++bx) {
        float ox = fminf(xhi, (float)(bx + 1)) - fmaxf(xi, (float)bx);
        float* row = dmap + (size_t)bx * NBY_;
        for (int by = by0; by <= bye; ++by) {
            float oy = fminf(yhi, (float)(by + 1)) - fmaxf(yi, (float)by);
            if (oy > 0.0f) atomicAdd(row + by, ox * oy);
        }
    }
}
__global__ void reduce1_k(const float* __restrict__ dmap, const unsigned char* __restrict__ pm,
                          float* __restrict__ psum, float* __restrict__ pmax) {
    float s = 0.0f, m = 0.0f;
    int stride = gridDim.x * blockDim.x;
    for (int i = blockIdx.x * blockDim.x + threadIdx.x; i < NBINS; i += stride) {
        float d = dmap[i];
        if (pm[i]) d = TDv;
        s += fmaxf(d - TDv, 0.0f);
        m = fmaxf(m, d);
    }
    __shared__ float ss[4], sm[4];
    int lane = threadIdx.x & 63, wv = threadIdx.x >> 6;
    wave_red(s, m);
    if (lane == 0) { ss[wv] = s; sm[wv] = m; }
    __syncthreads();
    if (threadIdx.x == 0) {
        float S = ss[0], M = sm[0];
        for (int w = 1; w < 4; ++w) { S += ss[w]; M = fmaxf(M, sm[w]); }
        psum[blockIdx.x] = S; pmax[blockIdx.x] = M;
    }
}
__global__ void reduce2_k(const float* __restrict__ psum, const float* __restrict__ pmax,
                          float* __restrict__ out, int n) {
    float s = 0.0f, m = 0.0f;
    for (int i = threadIdx.x; i < n; i += blockDim.x) { s += psum[i]; m = fmaxf(m, pmax[i]); }
    __shared__ float ss[16], sm[16];
    int lane = threadIdx.x & 63, wv = threadIdx.x >> 6;
    wave_red(s, m);
    if (lane == 0) { ss[wv] = s; sm[wv] = m; }
    __syncthreads();
    if (threadIdx.x == 0) {
        float S = 0.0f, M = 0.0f;
        for (int w = 0; w < (int)(blockDim.x >> 6); ++w) { S += ss[w]; M = fmaxf(M, sm[w]); }
        out[0] = S; out[1] = M;
    }
}
// -----------------------------------------------------------------------------

extern "C" void kernel_launch(void* const* d_in, const int* in_sizes, int n_in,
                              void* d_out, int out_size, void* d_ws, size_t ws_size,
                              hipStream_t stream) {
    const float* pos = (const float*)d_in[0];
    const float* xs = pos;
    const float* ys = pos + NTOT;
    const float* sxs = (const float*)d_in[1];
    const float* sys = (const float*)d_in[2];
    const unsigned char* pm = (const unsigned char*)d_in[5];
    float* out = (float*)d_out;

    float* S = (float*)d_ws;
    float* U = S + NBINS;
    float* V = U + NBINS;
    float* W = V + NBINS;
    float* segV = W + NBINS;
    float* segW = segV + SEGS * NBY_;
    float* psum = segW + SEGS * NBY_;
    float* pmax = psum + 64;
    size_t need = ((size_t)4 * NBINS + 2 * SEGS * NBY_ + 128) * sizeof(float);

    if (ws_size >= need) {
        hipMemsetAsync(d_ws, 0, (size_t)4 * NBINS * sizeof(float), stream);
        scatter_all_k<<<MOV_BLOCKS + FIX_BLOCKS, 256, 0, stream>>>(xs, ys, sxs, sys, S, U, V, W);
        scan_y_k<<<NBX_, 256, 0, stream>>>(U, W);
        colsum_k<<<SEGS * 4, 256, 0, stream>>>(V, W, segV, segW);
        final_k<<<SEGS * 4, 256, 0, stream>>>(S, U, V, W, segV, segW, pm, psum, pmax);
        combine_k<<<1, 64, 0, stream>>>(psum, pmax, out, SEGS * 4);
    } else {
        float* dmap = (float*)d_ws;
        float* ps = dmap + NBINS;
        float* pmx = ps + 1024;
        hipMemsetAsync(d_ws, 0, (size_t)NBINS * sizeof(float), stream);
        scatter_fixed_k<<<(NT_ * 22 + 255) / 256, 256, 0, stream>>>(xs, ys, sxs, sys, dmap);
        scatter_mov_k<<<(NM_ + NF_ + 255) / 256, 256, 0, stream>>>(xs, ys, sxs, sys, dmap);
        reduce1_k<<<1024, 256, 0, stream>>>(dmap, pm, ps, pmx);
        reduce2_k<<<1, 1024, 0, stream>>>(ps, pmx, out, 1024);
    }
}

// Round 3
// 481.370 us; speedup vs baseline: 3.0434x; 1.7671x over previous
//
#include <hip/hip_runtime.h>

#define NM_ 1500000
#define NT_ 100000
#define NF_ 1500000
#define NTOT (NM_ + NT_ + NF_)
#define NBX_ 1024
#define NBY_ 1024
#define NBINS (NBX_ * NBY_)
#define TDv 0.9f
#define NTIL 1024          /* 32x32 tiles of 32x32 bins */
#define NBLK 256           /* binning blocks */
#define CAPN 3800000u      /* item capacity; expected ~3.40M (see analysis) */

// Enumerate the <=4 tiles a footprint [bx0..bxe]x[by0..bye] covers
// (max span 22 bins <= tile size 32, so at most 2 tiles per axis).
struct TileSet { int t[4]; int n; };
__device__ inline TileSet tiles_of(int bx0, int bxe, int by0, int bye) {
    TileSet s;
    int txa = bx0 >> 5, txb = bxe >> 5, tya = by0 >> 5, tyb = bye >> 5;
    s.n = 0;
    s.t[s.n++] = (txa << 5) | tya;
    if (txb != txa) s.t[s.n++] = (txb << 5) | tya;
    if (tyb != tya) {
        s.t[s.n++] = (txa << 5) | tyb;
        if (txb != txa) s.t[s.n++] = (txb << 5) | tyb;
    }
    return s;
}

// Pass 1: per-block LDS histogram of (item, tile) pairs over all nodes.
__global__ void count_k(const float* __restrict__ xs, const float* __restrict__ ys,
                        const float* __restrict__ sxs, const float* __restrict__ sys,
                        unsigned* __restrict__ hist) {
    __shared__ unsigned lh[NTIL];
    for (int j = threadIdx.x; j < NTIL; j += 256) lh[j] = 0u;
    __syncthreads();
    int stride = NBLK * 256;
    for (int i = blockIdx.x * 256 + threadIdx.x; i < NTOT; i += stride) {
        float xi = xs[i], yi = ys[i];
        int bx0 = (int)xi, bxe = (int)(xi + sxs[i]);
        int by0 = (int)yi, bye = (int)(yi + sys[i]);
        TileSet ts = tiles_of(bx0, bxe, by0, bye);
        for (int j = 0; j < ts.n; ++j) atomicAdd(&lh[ts.t[j]], 1u);
    }
    __syncthreads();
    for (int j = threadIdx.x; j < NTIL; j += 256) hist[j * NBLK + blockIdx.x] = lh[j];
}

// Pass 1b: per-tile exclusive prefix over the NBLK block-counts (in place),
// and the tile total.
__global__ void offsets_k(unsigned* __restrict__ hist, unsigned* __restrict__ tileTotal) {
    int t = blockIdx.x, tid = threadIdx.x;
    unsigned c = hist[t * NBLK + tid];
    int lane = tid & 63, wv = tid >> 6;
    unsigned run = c;
    #pragma unroll
    for (int off = 1; off < 64; off <<= 1) {
        unsigned nn = __shfl_up(run, off, 64);
        if (lane >= off) run += nn;
    }
    __shared__ unsigned wt[4];
    if (lane == 63) wt[wv] = run;
    __syncthreads();
    unsigned base = 0;
    for (int w = 0; w < wv; ++w) base += wt[w];
    unsigned excl = base + run - c;
    hist[t * NBLK + tid] = excl;
    if (tid == NBLK - 1) tileTotal[t] = excl + c;
}

// Pass 1c: exclusive scan of the 1024 tile totals (one wave, 16 tiles/lane).
__global__ void scan_tiles_k(const unsigned* __restrict__ tot, unsigned* __restrict__ start) {
    int lane = threadIdx.x;
    unsigned c[16];
    unsigned s = 0;
    for (int j = 0; j < 16; ++j) { c[j] = tot[lane * 16 + j]; s += c[j]; }
    unsigned run = s;
    #pragma unroll
    for (int off = 1; off < 64; off <<= 1) {
        unsigned nn = __shfl_up(run, off, 64);
        if (lane >= off) run += nn;
    }
    unsigned base = run - s;
    for (int j = 0; j < 16; ++j) { start[lane * 16 + j] = base; base += c[j]; }
}

// Pass 2: scatter items (payload float4 or 4B node index) into tile buckets.
// Fixed nodes flagged by negated sx in payload mode (sx >= 0.5 always).
__global__ void place_k(const float* __restrict__ xs, const float* __restrict__ ys,
                        const float* __restrict__ sxs, const float* __restrict__ sys,
                        const unsigned* __restrict__ off, const unsigned* __restrict__ tileStart,
                        unsigned* __restrict__ idxbuf, float4* __restrict__ paybuf, int payload) {
    __shared__ unsigned sOff[NTIL];
    __shared__ unsigned lcnt[NTIL];
    int b = blockIdx.x;
    for (int j = threadIdx.x; j < NTIL; j += 256) {
        sOff[j] = tileStart[j] + off[j * NBLK + b];
        lcnt[j] = 0u;
    }
    __syncthreads();
    int stride = NBLK * 256;
    for (int i = b * 256 + threadIdx.x; i < NTOT; i += stride) {
        float xi = xs[i], yi = ys[i], sxi = sxs[i], syi = sys[i];
        int bx0 = (int)xi, bxe = (int)(xi + sxi);
        int by0 = (int)yi, bye = (int)(yi + syi);
        TileSet ts = tiles_of(bx0, bxe, by0, bye);
        bool isfix = (i >= NM_) && (i < NM_ + NT_);
        for (int j = 0; j < ts.n; ++j) {
            int tl = ts.t[j];
            unsigned r = atomicAdd(&lcnt[tl], 1u);
            unsigned p = sOff[tl] + r;
            if (p < CAPN) {
                if (payload) {
                    float4 v; v.x = xi; v.y = yi; v.z = isfix ? -sxi : sxi; v.w = syi;
                    paybuf[p] = v;
                } else {
                    idxbuf[p] = (unsigned)i;
                }
            }
        }
    }
}

// Pass 3: one block per tile. Accumulate exact overlap areas into an LDS
// tile (32x32, leading dim 33), then fused padding-mask + sum/max reduce.
// The global density map is never materialized; zero global atomics.
__global__ void accum_k(const float* __restrict__ xs, const float* __restrict__ ys,
                        const float* __restrict__ sxs, const float* __restrict__ sys,
                        const unsigned* __restrict__ tileStart, const unsigned* __restrict__ tileTotal,
                        const unsigned* __restrict__ idxbuf, const float4* __restrict__ paybuf, int payload,
                        const unsigned char* __restrict__ pm,
                        float* __restrict__ psum, float* __restrict__ pmax) {
    __shared__ float sm[32 * 33];
    int t = blockIdx.x;
    int baseX = (t >> 5) << 5, baseY = (t & 31) << 5;
    for (int j = threadIdx.x; j < 32 * 33; j += 256) sm[j] = 0.0f;
    __syncthreads();
    unsigned s0 = tileStart[t], n = tileTotal[t];
    for (unsigned k = threadIdx.x; k < n; k += 256) {
        unsigned p = s0 + k;
        if (p >= CAPN) break;     // capacity guard (never triggers at CAPN=3.8M)
        float xi, yi, sxi, syi, w;
        if (payload) {
            float4 v = paybuf[p];
            xi = v.x; yi = v.y; sxi = v.z; syi = v.w; w = 1.0f;
            if (sxi < 0.0f) { sxi = -sxi; w = TDv; }
        } else {
            unsigned i = idxbuf[p];
            xi = xs[i]; yi = ys[i]; sxi = sxs[i]; syi = sys[i];
            w = (i >= NM_ && i < NM_ + NT_) ? TDv : 1.0f;
        }
        float xhi = xi + sxi, yhi = yi + syi;
        int bx0 = (int)xi, bxe = (int)xhi, by0 = (int)yi, bye = (int)yhi;
        int cxa = max(bx0, baseX), cxe = min(bxe, baseX + 31);
        int cya = max(by0, baseY), cye = min(bye, baseY + 31);
        for (int bx = cxa; bx <= cxe; ++bx) {
            float ox = fminf(xhi, (float)(bx + 1)) - fmaxf(xi, (float)bx);
            float wox = w * fmaxf(ox, 0.0f);
            int rb = (bx - baseX) * 33 - baseY;
            for (int by = cya; by <= cye; ++by) {
                float oy = fminf(yhi, (float)(by + 1)) - fmaxf(yi, (float)by);
                atomicAdd(&sm[rb + by], wox * fmaxf(oy, 0.0f));
            }
        }
    }
    __syncthreads();
    // fused reduce: each thread owns 4 consecutive bins of one row
    int r = threadIdx.x >> 3, c = (threadIdx.x & 7) * 4;
    uchar4 pmv = *(const uchar4*)&pm[(size_t)(baseX + r) * NBY_ + baseY + c];
    const unsigned char* pmp = (const unsigned char*)&pmv;
    float acc = 0.0f, mx = 0.0f;
    for (int j = 0; j < 4; ++j) {
        float d = sm[r * 33 + c + j];
        if (pmp[j]) d = TDv;
        acc += fmaxf(d - TDv, 0.0f);
        mx = fmaxf(mx, d);
    }
    int lane = threadIdx.x & 63, wv = threadIdx.x >> 6;
    for (int off2 = 32; off2 > 0; off2 >>= 1) {
        acc += __shfl_down(acc, off2, 64);
        mx = fmaxf(mx, __shfl_down(mx, off2, 64));
    }
    __shared__ float ssum[4], smax[4];
    if (lane == 0) { ssum[wv] = acc; smax[wv] = mx; }
    __syncthreads();
    if (threadIdx.x == 0) {
        float S = ssum[0], M = smax[0];
        for (int w2 = 1; w2 < 4; ++w2) { S += ssum[w2]; M = fmaxf(M, smax[w2]); }
        psum[t] = S;
        pmax[t] = M;
    }
}

__global__ void combine_k(const float* __restrict__ psum, const float* __restrict__ pmax,
                          float* __restrict__ out) {
    float s = 0.0f, m = 0.0f;
    for (int i = threadIdx.x; i < NTIL; i += 256) { s += psum[i]; m = fmaxf(m, pmax[i]); }
    int lane = threadIdx.x & 63, wv = threadIdx.x >> 6;
    for (int off = 32; off > 0; off >>= 1) {
        s += __shfl_down(s, off, 64);
        m = fmaxf(m, __shfl_down(m, off, 64));
    }
    __shared__ float ss[4], sm_[4];
    if (lane == 0) { ss[wv] = s; sm_[wv] = m; }
    __syncthreads();
    if (threadIdx.x == 0) {
        float S = 0.0f, M = 0.0f;
        for (int w = 0; w < 4; ++w) { S += ss[w]; M = fmaxf(M, sm_[w]); }
        out[0] = S;   // density_cost
        out[1] = M;   // max_density (bin_area == 1)
    }
}

extern "C" void kernel_launch(void* const* d_in, const int* in_sizes, int n_in,
                              void* d_out, int out_size, void* d_ws, size_t ws_size,
                              hipStream_t stream) {
    const float* pos = (const float*)d_in[0];
    const float* xs = pos;
    const float* ys = pos + NTOT;
    const float* sxs = (const float*)d_in[1];
    const float* sys = (const float*)d_in[2];
    const unsigned char* pm = (const unsigned char*)d_in[5];
    float* out = (float*)d_out;

    unsigned* hist = (unsigned*)d_ws;              // NTIL*NBLK = 1 MB
    unsigned* tileTotal = hist + NTIL * NBLK;      // 1024
    unsigned* tileStart = tileTotal + NTIL;        // 1024
    float* psum = (float*)(tileStart + NTIL);      // 1024
    float* pmax = psum + NTIL;                     // 1024
    void* buf = (void*)(pmax + NTIL);              // 16B-aligned item buffer
    size_t base = (size_t)(NTIL * NBLK + 4 * NTIL) * sizeof(unsigned);

    // payload mode (float4 items, streaming reads in accum) if ws allows;
    // index mode (4B items, gather in accum) needs 16.27 MB — known to fit.
    int payload = (ws_size >= base + (size_t)CAPN * sizeof(float4)) ? 1 : 0;

    hipMemsetAsync(hist, 0, (size_t)NTIL * NBLK * sizeof(unsigned), stream);
    count_k<<<NBLK, 256, 0, stream>>>(xs, ys, sxs, sys, hist);
    offsets_k<<<NTIL, NBLK, 0, stream>>>(hist, tileTotal);
    scan_tiles_k<<<1, 64, 0, stream>>>(tileTotal, tileStart);
    place_k<<<NBLK, 256, 0, stream>>>(xs, ys, sxs, sys, hist, tileStart,
                                      (unsigned*)buf, (float4*)buf, payload);
    accum_k<<<NTIL, 256, 0, stream>>>(xs, ys, sxs, sys, tileStart, tileTotal,
                                      (const unsigned*)buf, (const float4*)buf, payload,
                                      pm, psum, pmax);
    combine_k<<<1, 256, 0, stream>>>(psum, pmax, out);
}

// Round 4
// 423.585 us; speedup vs baseline: 3.4586x; 1.1364x over previous
//
#include <hip/hip_runtime.h>

#define NM_ 1500000
#define NT_ 100000
#define NF_ 1500000
#define NTOT (NM_ + NT_ + NF_)
#define NBY_ 1024
#define TDv 0.9f

// item word encoding (index mode): (node_idx << 5) | k
//   k in [0,29]  : fixed-node column item, bin column = (int)x + k
//   k == 30     : whole fixed node (fallback mode)
//   k == 31     : movable/filler node (full footprint)
#define K_MOV 31
#define K_FIXFULL 30

#define CAP2 6000000u    /* primary item capacity (expected ~5.39M) */
#define CAP1 3800000u    /* fallback capacity (R3-proven, ~3.40M expected) */

// ---------------------------------------------------------------- count ----
template<int SHY, bool SPLIT, int NB>
__global__ void count_k(const float* __restrict__ xs, const float* __restrict__ ys,
                        const float* __restrict__ sxs, const float* __restrict__ sys,
                        unsigned* __restrict__ hist) {
    constexpr int NTILY = NBY_ >> SHY;
    constexpr int NTILES = 32 * NTILY;
    __shared__ unsigned lh[NTILES];
    for (int j = threadIdx.x; j < NTILES; j += 256) lh[j] = 0u;
    __syncthreads();
    for (int i = blockIdx.x * 256 + threadIdx.x; i < NTOT; i += NB * 256) {
        float xi = xs[i], yi = ys[i];
        float xhi = xi + sxs[i], yhi = yi + sys[i];
        int bx0 = (int)xi, bxe = (int)xhi;
        int tya = (int)yi >> SHY, tyb = (int)yhi >> SHY;
        bool isfix = (i >= NM_) && (i < NM_ + NT_);
        if (SPLIT && isfix) {
            for (int bx = bx0; bx <= bxe; ++bx) {
                int tx = bx >> 5;
                for (int ty = tya; ty <= tyb; ++ty) atomicAdd(&lh[tx * NTILY + ty], 1u);
            }
        } else {
            int txa = bx0 >> 5, txb = bxe >> 5;
            for (int tx = txa; tx <= txb; ++tx)
                for (int ty = tya; ty <= tyb; ++ty) atomicAdd(&lh[tx * NTILY + ty], 1u);
        }
    }
    __syncthreads();
    for (int j = threadIdx.x; j < NTILES; j += 256)
        hist[(size_t)j * NB + blockIdx.x] = lh[j];   // fully written -> no memset needed
}

// ------------------------------------------------------------- offsets ----
// Per-tile exclusive scan (in place) of the NB per-block counts + tile total.
template<int NB>
__global__ void offsets_k(unsigned* __restrict__ hist, unsigned* __restrict__ tileTotal) {
    constexpr int C = NB / 256;
    int t = blockIdx.x, tid = threadIdx.x;
    unsigned* row = hist + (size_t)t * NB;
    unsigned c[C], s = 0;
    #pragma unroll
    for (int j = 0; j < C; ++j) { c[j] = row[tid * C + j]; s += c[j]; }
    int lane = tid & 63, wv = tid >> 6;
    unsigned run = s;
    #pragma unroll
    for (int off = 1; off < 64; off <<= 1) {
        unsigned nn = __shfl_up(run, off, 64);
        if (lane >= off) run += nn;
    }
    __shared__ unsigned wt[4];
    if (lane == 63) wt[wv] = run;
    __syncthreads();
    unsigned base = 0;
    for (int w = 0; w < wv; ++w) base += wt[w];
    base += run - s;                       // exclusive prefix for this thread
    #pragma unroll
    for (int j = 0; j < C; ++j) { row[tid * C + j] = base; base += c[j]; }
    if (tid == 255) tileTotal[t] = base;   // grand total of this tile
}

// Exclusive scan of NTILES tile totals (single block).
template<int NTILES>
__global__ void scan_tiles_k(const unsigned* __restrict__ tot, unsigned* __restrict__ start) {
    constexpr int C = NTILES / 256;
    int tid = threadIdx.x;
    unsigned c[C], s = 0;
    #pragma unroll
    for (int j = 0; j < C; ++j) { c[j] = tot[tid * C + j]; s += c[j]; }
    int lane = tid & 63, wv = tid >> 6;
    unsigned run = s;
    #pragma unroll
    for (int off = 1; off < 64; off <<= 1) {
        unsigned nn = __shfl_up(run, off, 64);
        if (lane >= off) run += nn;
    }
    __shared__ unsigned wt[4];
    if (lane == 63) wt[wv] = run;
    __syncthreads();
    unsigned base = 0;
    for (int w = 0; w < wv; ++w) base += wt[w];
    base += run - s;
    #pragma unroll
    for (int j = 0; j < C; ++j) { start[tid * C + j] = base; base += c[j]; }
}

// --------------------------------------------------------------- place ----
template<int SHY, bool SPLIT, int NB>
__global__ void place_k(const float* __restrict__ xs, const float* __restrict__ ys,
                        const float* __restrict__ sxs, const float* __restrict__ sys,
                        const unsigned* __restrict__ off, const unsigned* __restrict__ tileStart,
                        unsigned* __restrict__ idxbuf, float4* __restrict__ paybuf,
                        int payload, unsigned cap) {
    constexpr int NTILY = NBY_ >> SHY;
    constexpr int NTILES = 32 * NTILY;
    __shared__ unsigned sOff[NTILES];
    __shared__ unsigned lcnt[NTILES];
    int b = blockIdx.x;
    for (int j = threadIdx.x; j < NTILES; j += 256) {
        sOff[j] = tileStart[j] + off[(size_t)j * NB + b];
        lcnt[j] = 0u;
    }
    __syncthreads();
    for (int i = b * 256 + threadIdx.x; i < NTOT; i += NB * 256) {
        float xi = xs[i], yi = ys[i], sxi = sxs[i], syi = sys[i];
        float xhi = xi + sxi, yhi = yi + syi;
        int bx0 = (int)xi, bxe = (int)xhi;
        int tya = (int)yi >> SHY, tyb = (int)yhi >> SHY;
        bool isfix = (i >= NM_) && (i < NM_ + NT_);
        if (SPLIT && isfix) {
            for (int bx = bx0; bx <= bxe; ++bx) {
                int tx = bx >> 5;
                float x0 = fmaxf(xi, (float)bx);
                float wid = fminf(xhi, (float)(bx + 1)) - x0;
                unsigned item = ((unsigned)i << 5) | (unsigned)(bx - bx0);
                for (int ty = tya; ty <= tyb; ++ty) {
                    unsigned r = atomicAdd(&lcnt[tx * NTILY + ty], 1u);
                    unsigned p = sOff[tx * NTILY + ty] + r;
                    if (p < cap) {
                        if (payload) { float4 v; v.x = x0; v.y = yi; v.z = -wid; v.w = syi; paybuf[p] = v; }
                        else idxbuf[p] = item;
                    }
                }
            }
        } else {
            int txa = bx0 >> 5, txb = bxe >> 5;
            unsigned item = ((unsigned)i << 5) | (unsigned)(isfix ? K_FIXFULL : K_MOV);
            for (int tx = txa; tx <= txb; ++tx)
                for (int ty = tya; ty <= tyb; ++ty) {
                    unsigned r = atomicAdd(&lcnt[tx * NTILY + ty], 1u);
                    unsigned p = sOff[tx * NTILY + ty] + r;
                    if (p < cap) {
                        if (payload) { float4 v; v.x = xi; v.y = yi; v.z = isfix ? -sxi : sxi; v.w = syi; paybuf[p] = v; }
                        else idxbuf[p] = item;
                    }
                }
        }
    }
}

// --------------------------------------------------------------- accum ----
// One block per 32 x TSY bin tile; LDS accumulation; fused mask + sum/max.
template<int SHY>
__global__ void accum_k(const float* __restrict__ xs, const float* __restrict__ ys,
                        const float* __restrict__ sxs, const float* __restrict__ sys,
                        const unsigned* __restrict__ tileStart, const unsigned* __restrict__ tileTotal,
                        const unsigned* __restrict__ idxbuf, const float4* __restrict__ paybuf,
                        int payload, unsigned cap,
                        const unsigned char* __restrict__ pm,
                        float* __restrict__ psum, float* __restrict__ pmax) {
    constexpr int TSY = 1 << SHY;
    constexpr int NTILY = NBY_ >> SHY;
    __shared__ float sm[32 * TSY];
    int t = blockIdx.x;
    int baseX = (t / NTILY) * 32, baseY = (t % NTILY) * TSY;
    for (int j = threadIdx.x; j < 32 * TSY; j += 256) sm[j] = 0.0f;
    __syncthreads();
    unsigned s0 = tileStart[t], n = tileTotal[t];
    for (unsigned k = threadIdx.x; k < n; k += 256) {
        unsigned p = s0 + k;
        if (p >= cap) break;               // capacity guard (never triggers)
        float xi, yi, sxi, syi, w = 1.0f;
        int bxa, bxe2;
        if (payload) {
            float4 v = paybuf[p];
            xi = v.x; yi = v.y; sxi = v.z; syi = v.w;
            if (sxi < 0.0f) { sxi = -sxi; w = TDv; }
            bxa = (int)xi; bxe2 = (int)(xi + sxi);
        } else {
            unsigned it = idxbuf[p];
            unsigned i = it >> 5; int kk = (int)(it & 31u);
            xi = xs[i]; yi = ys[i]; sxi = sxs[i]; syi = sys[i];
            if (kk != K_MOV) w = TDv;
            int b0 = (int)xi;
            if (kk < K_FIXFULL) { bxa = bxe2 = b0 + kk; }
            else { bxa = b0; bxe2 = (int)(xi + sxi); }
        }
        float xhi = xi + sxi, yhi = yi + syi;
        int by0 = (int)yi, bye = (int)yhi;
        int cxa = max(bxa, baseX), cxe = min(bxe2, baseX + 31);
        int cya = max(by0, baseY), cye = min(bye, baseY + TSY - 1);
        for (int bx = cxa; bx <= cxe; ++bx) {
            float ox = fminf(xhi, (float)(bx + 1)) - fmaxf(xi, (float)bx);
            float wox = w * fmaxf(ox, 0.0f);
            int rb = (bx - baseX) * TSY - baseY;
            for (int by = cya; by <= cye; ++by) {
                float oy = fminf(yhi, (float)(by + 1)) - fmaxf(yi, (float)by);
                atomicAdd(&sm[rb + by], wox * fmaxf(oy, 0.0f));
            }
        }
    }
    __syncthreads();
    float acc = 0.0f, mx = 0.0f;
    for (int j = threadIdx.x; j < 32 * TSY; j += 256) {
        int r = j >> SHY, c = j & (TSY - 1);
        float d = sm[j];
        if (pm[(size_t)(baseX + r) * NBY_ + baseY + c]) d = TDv;
        acc += fmaxf(d - TDv, 0.0f);
        mx = fmaxf(mx, d);
    }
    int lane = threadIdx.x & 63, wv = threadIdx.x >> 6;
    for (int off2 = 32; off2 > 0; off2 >>= 1) {
        acc += __shfl_down(acc, off2, 64);
        mx = fmaxf(mx, __shfl_down(mx, off2, 64));
    }
    __shared__ float ssum[4], smax[4];
    if (lane == 0) { ssum[wv] = acc; smax[wv] = mx; }
    __syncthreads();
    if (threadIdx.x == 0) {
        float S = ssum[0], M = smax[0];
        for (int w2 = 1; w2 < 4; ++w2) { S += ssum[w2]; M = fmaxf(M, smax[w2]); }
        psum[t] = S;
        pmax[t] = M;
    }
}

__global__ void combine_k(const float* __restrict__ psum, const float* __restrict__ pmax,
                          float* __restrict__ out, int n) {
    float s = 0.0f, m = 0.0f;
    for (int i = threadIdx.x; i < n; i += 256) { s += psum[i]; m = fmaxf(m, pmax[i]); }
    int lane = threadIdx.x & 63, wv = threadIdx.x >> 6;
    for (int off = 32; off > 0; off >>= 1) {
        s += __shfl_down(s, off, 64);
        m = fmaxf(m, __shfl_down(m, off, 64));
    }
    __shared__ float ss[4], sm_[4];
    if (lane == 0) { ss[wv] = s; sm_[wv] = m; }
    __syncthreads();
    if (threadIdx.x == 0) {
        float S = 0.0f, M = 0.0f;
        for (int w = 0; w < 4; ++w) { S += ss[w]; M = fmaxf(M, sm_[w]); }
        out[0] = S;   // density_cost
        out[1] = M;   // max_density (bin_area == 1)
    }
}

extern "C" void kernel_launch(void* const* d_in, const int* in_sizes, int n_in,
                              void* d_out, int out_size, void* d_ws, size_t ws_size,
                              hipStream_t stream) {
    const float* pos = (const float*)d_in[0];
    const float* xs = pos;
    const float* ys = pos + NTOT;
    const float* sxs = (const float*)d_in[1];
    const float* sys = (const float*)d_in[2];
    const unsigned char* pm = (const unsigned char*)d_in[5];
    float* out = (float*)d_out;

    // ---- primary: 32x16 tiles (2048), column-split fixed nodes, NBLK=512
    {
        constexpr int NB = 512, NTILES = 2048;
        unsigned* hist = (unsigned*)d_ws;                       // NTILES*NB u32 = 4 MB
        unsigned* tileTotal = hist + (size_t)NTILES * NB;
        unsigned* tileStart = tileTotal + NTILES;
        float* psum = (float*)(tileStart + NTILES);
        float* pmax = psum + NTILES;
        void* buf = (void*)(pmax + NTILES);
        size_t meta = ((size_t)NTILES * NB + 4 * NTILES) * sizeof(unsigned);  // 16B-aligned
        int pay = (ws_size >= meta + (size_t)CAP2 * sizeof(float4)) ? 1 : 0;
        int idx = (ws_size >= meta + (size_t)CAP2 * sizeof(unsigned)) ? 1 : 0;
        if (pay || idx) {
            count_k<4, true, NB><<<NB, 256, 0, stream>>>(xs, ys, sxs, sys, hist);
            offsets_k<NB><<<NTILES, 256, 0, stream>>>(hist, tileTotal);
            scan_tiles_k<NTILES><<<1, 256, 0, stream>>>(tileTotal, tileStart);
            place_k<4, true, NB><<<NB, 256, 0, stream>>>(xs, ys, sxs, sys, hist, tileStart,
                                                         (unsigned*)buf, (float4*)buf, pay, CAP2);
            accum_k<4><<<NTILES, 256, 0, stream>>>(xs, ys, sxs, sys, tileStart, tileTotal,
                                                   (const unsigned*)buf, (const float4*)buf, pay, CAP2,
                                                   pm, psum, pmax);
            combine_k<<<1, 256, 0, stream>>>(psum, pmax, out, NTILES);
            return;
        }
    }
    // ---- fallback: 32x32 tiles (1024), whole-node items, NBLK=256 (16.27 MB, proven)
    {
        constexpr int NB = 256, NTILES = 1024;
        unsigned* hist = (unsigned*)d_ws;
        unsigned* tileTotal = hist + (size_t)NTILES * NB;
        unsigned* tileStart = tileTotal + NTILES;
        float* psum = (float*)(tileStart + NTILES);
        float* pmax = psum + NTILES;
        void* buf = (void*)(pmax + NTILES);
        count_k<5, false, NB><<<NB, 256, 0, stream>>>(xs, ys, sxs, sys, hist);
        offsets_k<NB><<<NTILES, 256, 0, stream>>>(hist, tileTotal);
        scan_tiles_k<NTILES><<<1, 256, 0, stream>>>(tileTotal, tileStart);
        place_k<5, false, NB><<<NB, 256, 0, stream>>>(xs, ys, sxs, sys, hist, tileStart,
                                                      (unsigned*)buf, (float4*)buf, 0, CAP1);
        accum_k<5><<<NTILES, 256, 0, stream>>>(xs, ys, sxs, sys, tileStart, tileTotal,
                                               (const unsigned*)buf, (const float4*)buf, 0, CAP1,
                                               pm, psum, pmax);
        combine_k<<<1, 256, 0, stream>>>(psum, pmax, out, NTILES);
    }
}